// Round 4
// baseline (100.020 us; speedup 1.0000x reference)
//
#include <hip/hip_runtime.h>
#include <hip/hip_bf16.h>

// LineCNNSimple: 1024 x (conv3x3 1->64 +relu, conv3x3 64->64 +relu, maxpool2,
// fc 12544->128 +relu, fc 128->83). bf16 MFMA pipeline.
// R4: conv2 on mfma_32x32x16, one base VGPR per M-tile + immediate ds offsets
//     (zero addr-VALU in K-loop), pool-in-register via reg-quad = 2x2 window.
//
// ws element(u16) offsets:
//   WB1  @0        : 2048    conv1 W frag [4nt][64lane][8], k==9 slot = bias
//   WB2  @2048     : 36864   conv2 W frag [2nh][36ks][64lane][8], k=(dy*3+dx)*64+ci
//   WFC1 @38912    : 1605632 fc1 W frag [8nt][392ks][64lane][8], k'=(oyp*14+oxp)*64+co
//   WFC2 @1644544  : 12288   fc2 W frag [6nt][4ks][64lane][8] (cls>=83 zeroed)
//   POOL @1656832  : 12845056 pooled acts [1024][12544] bf16 (k'-order)
//   PART @byte 29003776 : f16 fc1 partials [4q][64ig][16img][128fcn] (1MB)

typedef __attribute__((ext_vector_type(8))) short short8;
typedef __attribute__((ext_vector_type(4))) float f32x4;
typedef __attribute__((ext_vector_type(16))) float f32x16;

#define WB1_E   0u
#define WB2_E   2048u
#define WFC1_E  38912u
#define WFC2_E  1644544u
#define POOL_E  1656832u
#define PART_B  29003776u

__device__ __forceinline__ unsigned short f2bf(float f) {
  unsigned u = __float_as_uint(f);
  u += 0x7fffu + ((u >> 16) & 1u);   // round-to-nearest-even
  return (unsigned short)(u >> 16);
}

// ---------------- prep: repack weights to bf16 frag order ----------------
__global__ __launch_bounds__(256) void prep_kernel(
    const float* __restrict__ w1, const float* __restrict__ c1b,
    const float* __restrict__ w2, const float* __restrict__ wfc1,
    const float* __restrict__ wfc2, unsigned short* __restrict__ ws16)
{
  int i = blockIdx.x * blockDim.x + threadIdx.x;
  if (i < 2048) {
    int j = i & 7, l = (i >> 3) & 63, nt = i >> 9;
    int n = nt * 16 + (l & 15), k = 8 * (l >> 4) + j;
    float v = (k < 9) ? w1[n * 9 + k] : (k == 9 ? c1b[n] : 0.f);
    ws16[WB1_E + i] = f2bf(v);
  } else if (i < 38912) {
    int i2 = i - 2048;                // conv2 W for 32x32x16 MFMA
    int j = i2 & 7, l = (i2 >> 3) & 63, rest = i2 >> 9;
    int ks = rest % 36, nh = rest / 36;
    int co = nh * 32 + (l & 31);
    int k = ks * 16 + (l >> 5) * 8 + j;
    int dydx = k >> 6, ci = k & 63;
    ws16[WB2_E + i2] = f2bf(w2[co * 576 + ci * 9 + dydx]);
  } else if (i < 1644544) {
    int i2 = i - 38912;
    int j = i2 & 7, l = (i2 >> 3) & 63, rest = i2 >> 9;
    int ks = rest % 392, nt = rest / 392;
    int fcn = nt * 16 + (l & 15);
    int kp = ks * 32 + 8 * (l >> 4) + j;
    int co = kp & 63, r2 = kp >> 6;
    int oxp = r2 % 14, oyp = r2 / 14;
    ws16[WFC1_E + i2] = f2bf(wfc1[fcn * 12544 + co * 196 + oyp * 14 + oxp]);
  } else if (i < 1656832) {
    int i2 = i - 1644544;
    int j = i2 & 7, l = (i2 >> 3) & 63, rest = i2 >> 9;
    int ks = rest & 3, nt = rest >> 2;
    int cls = nt * 16 + (l & 15);
    int k = ks * 32 + 8 * (l >> 4) + j;
    float v = (cls < 83) ? wfc2[cls * 128 + k] : 0.f;
    ws16[WFC2_E + i2] = f2bf(v);
  }
}

// ---------------- fused conv1+conv2+pool; one (image, row-half) per block ----
// lds1: [18 rows][30 cols] cells x 144 B (64 u16 co + 8 u16 pad) = 77,760 B
// xw:   padded 30x30 bf16 input @ 77760, 1800 B
__global__ __launch_bounds__(512, 4) void conv_kernel(
    const float* __restrict__ x, const float* __restrict__ c2b,
    unsigned short* __restrict__ ws16)
{
  extern __shared__ char smem[];
  unsigned short* xw = (unsigned short*)(smem + 77760);

  const int tid = threadIdx.x;
  const int wave = tid >> 6, lane = tid & 63;
  const int bid = blockIdx.x;
  const int n = bid >> 1, hf = bid & 1;
  const int rlo = hf ? 15 : 0;          // first conv1 output row this half
  const int M1 = hf ? 364 : 476;        // conv1 positions this half
  const int T1 = hf ? 23 : 30;          // conv1 16-tiles (ceil)
  const int lr_off = hf ? -15 : 1;      // conv1 store row: lr = rr + lr_off

  const short8* wb1 = (const short8*)(ws16 + WB1_E);
  unsigned short* poolg = ws16 + POOL_E + (unsigned)n * 12544u;

  short8 z8 = {0, 0, 0, 0, 0, 0, 0, 0};
  // zero lds1 (incl pads); stage padded window (bounds folded in)
  {
    short8* l8 = (short8*)smem;
    for (int idx = tid; idx < 4860; idx += 512) l8[idx] = z8;
    const float* xg = x + (n >> 5) * 25088 + (n & 31) * 28;
    for (int i = tid; i < 900; i += 512) {
      int yy = (i * 2185) >> 16;        // i/30
      int xx = i - yy * 30;
      int iy = yy - 1, ix = xx - 1;
      bool inb = (iy >= 0) && (iy < 28) && (ix >= 0) && (ix < 28);
      float v = inb ? xg[iy * 896 + ix] : 0.f;
      xw[i] = f2bf(v);
    }
  }
  __syncthreads();

  // ---- conv1 (16x16x32): weights as A-operand; compile-time LDS offsets
  {
    const int g = lane >> 4, l15 = lane & 15;
    short8 b1f[4];
#pragma unroll
    for (int nt = 0; nt < 4; ++nt) b1f[nt] = wb1[nt * 64 + lane];
    for (int mt = wave; mt < T1; mt += 8) {
      int m = mt * 16 + l15;
      bool mval = m < M1;
      int mc = mval ? m : M1 - 1;
      int yr = (mc * 2341) >> 16;       // mc/28
      int rr = rlo + yr;
      int ox = mc - yr * 28;
      const char* xb = (const char*)xw + (rr * 30 + ox) * 2;
      short8 a = z8;
      if (g == 0) {                     // k = 0..7  (dy*3+dx)
        a[0] = *(const short*)(xb + 0);
        a[1] = *(const short*)(xb + 2);
        a[2] = *(const short*)(xb + 4);
        a[3] = *(const short*)(xb + 60);
        a[4] = *(const short*)(xb + 62);
        a[5] = *(const short*)(xb + 64);
        a[6] = *(const short*)(xb + 120);
        a[7] = *(const short*)(xb + 122);
      } else if (g == 1) {              // k = 8, k = 9 bias lane
        a[0] = *(const short*)(xb + 124);
        a[1] = (short)0x3F80;           // 1.0 bf16
      }
      f32x4 d[4];
#pragma unroll
      for (int nt = 0; nt < 4; ++nt) {
        f32x4 zz = {0.f, 0.f, 0.f, 0.f};
        d[nt] = __builtin_amdgcn_mfma_f32_16x16x32_bf16(b1f[nt], a, zz, 0, 0, 0);
      }
      if (mval) {                       // D: row=co 4g+i, col=own l15 -> m
        int spB = ((rr + lr_off) * 30 + ox + 1) * 144;
#pragma unroll
        for (int nt = 0; nt < 4; ++nt)
#pragma unroll
          for (int t = 0; t < 2; ++t) {
            int co2 = nt * 16 + 4 * g + 2 * t;
            unsigned pk = (unsigned)f2bf(fmaxf(d[nt][2 * t], 0.f)) |
                          ((unsigned)f2bf(fmaxf(d[nt][2 * t + 1], 0.f)) << 16);
            *(unsigned*)(smem + (spB + co2 * 2)) = pk;
          }
      }
    }
  }
  __syncthreads();

  // ---- conv2 (32x32x16): M-tile = 8 pool-windows (m = 4*win + 2*dy2+dx2)
  // wave = nh (co half) x wg; <=4 M-tiles/wave, 1 base VGPR each, imm ds offsets
  {
    const int nh = wave >> 2;
    const int wg = wave & 3;
    const int l31 = lane & 31;
    const int h = lane >> 5;
    const int T32 = hf ? 11 : 14;       // M-tiles this half (hf1 tile 10 padded)
    const int Wh  = hf ? 84 : 112;      // valid windows this half
    const float bias = c2b[nh * 32 + l31];
    const short8* wb2w = (const short8*)(ws16 + WB2_E) + nh * 2304 + lane;

    int baseB[4];
#pragma unroll
    for (int t = 0; t < 4; ++t) {
      int tI = wg + 4 * t;
      int lw = tI * 8 + (l31 >> 2);     // window (may exceed Wh for pad tiles)
      int py = lw / 14, px = lw % 14;
      int R = 2 * py + ((l31 >> 1) & 1);
      int C = 2 * px + (l31 & 1);
      baseB[t] = (R * 30 + C) * 144 + h * 16;
    }
    f32x16 acc[4];
#pragma unroll
    for (int t = 0; t < 4; ++t) acc[t] = (f32x16)(0.0f);

#pragma unroll
    for (int ph = 0; ph < 9; ++ph) {    // ph = dy*3+dx, fully unrolled
      const int cellO = ((ph / 3) * 30 + (ph % 3)) * 144;
      short8 bf[4];
#pragma unroll
      for (int ksb = 0; ksb < 4; ++ksb) bf[ksb] = wb2w[(ph * 4 + ksb) * 64];
#pragma unroll
      for (int t = 0; t < 4; ++t) {
        if (wg + 4 * t < T32) {         // wave-uniform
#pragma unroll
          for (int ksb = 0; ksb < 4; ++ksb) {
            short8 a = *(const short8*)(smem + (baseB[t] + (cellO + 32 * ksb)));
            acc[t] = __builtin_amdgcn_mfma_f32_32x32x16_bf16(a, bf[ksb], acc[t], 0, 0, 0);
          }
        }
      }
    }
    // epilogue: reg-quad q = window 2q+h; 2x2 max + bias + relu -> global
#pragma unroll
    for (int t = 0; t < 4; ++t) {
      int tI = wg + 4 * t;
      if (tI < T32) {
#pragma unroll
        for (int q = 0; q < 4; ++q) {
          int lw = tI * 8 + 2 * q + h;
          if (lw < Wh) {
            float p = fmaxf(fmaxf(acc[t][4 * q + 0], acc[t][4 * q + 1]),
                            fmaxf(acc[t][4 * q + 2], acc[t][4 * q + 3]));
            p = fmaxf(p + bias, 0.f);
            poolg[(hf * 112 + lw) * 64 + nh * 32 + l31] = f2bf(p);
          }
        }
      }
    }
  }
}

// ---------------- fc1 stage A: 256 blocks = 64 img-groups x 4 K-slices ----
__global__ __launch_bounds__(512) void fc1_kernel(unsigned short* __restrict__ ws16)
{
  extern __shared__ char smem[];
  short8* A8 = (short8*)smem;              // [16 img][393 short8] (stride pad)
  const int tid = threadIdx.x;
  const int wave = tid >> 6, lane = tid & 63;
  const int g = lane >> 4, l15 = lane & 15;
  const int ig = blockIdx.x >> 2, q = blockIdx.x & 3;
  const short8* pool8 = (const short8*)(ws16 + POOL_E);
  const short8* wf1 = (const short8*)(ws16 + WFC1_E);
  {
    int img = tid >> 5, l32 = tid & 31;
    const short8* src = pool8 + (ig * 16 + img) * 1568 + q * 392;
#pragma unroll
    for (int j = 0; j < 13; ++j) {
      int idx = l32 + 32 * j;
      if (idx < 392) A8[img * 393 + idx] = src[idx];
    }
  }
  __syncthreads();
  f32x4 accA = {0.f, 0.f, 0.f, 0.f}, accB = {0.f, 0.f, 0.f, 0.f};
  const short8* wbase = wf1 + (wave * 392 + q * 98) * 64 + lane;
#pragma unroll 2
  for (int ks = 0; ks < 98; ++ks) {
    short8 b = wbase[ks * 64];
    short8 a = A8[l15 * 393 + ks * 4 + g];
    if (ks & 1) accB = __builtin_amdgcn_mfma_f32_16x16x32_bf16(a, b, accB, 0, 0, 0);
    else        accA = __builtin_amdgcn_mfma_f32_16x16x32_bf16(a, b, accA, 0, 0, 0);
  }
  _Float16* part = (_Float16*)((char*)ws16 + PART_B);
  int base = ((q * 64 + ig) * 16 + 4 * g) * 128 + wave * 16 + l15;
#pragma unroll
  for (int i = 0; i < 4; ++i) part[base + i * 128] = (_Float16)(accA[i] + accB[i]);
}

// ---------------- fc stage B: sum 4 partials + bias/relu + fc2 ----
__global__ __launch_bounds__(512) void fc2_kernel(
    const float* __restrict__ b1, const float* __restrict__ b2,
    const unsigned short* __restrict__ ws16, float* __restrict__ out)
{
  __shared__ unsigned short h_s[16 * 136];
  const int tid = threadIdx.x;
  const int wave = tid >> 6, lane = tid & 63;
  const int g = lane >> 4, l15 = lane & 15;
  const int ig = blockIdx.x;
  const _Float16* part = (const _Float16*)((const char*)ws16 + PART_B);
#pragma unroll
  for (int t = 0; t < 4; ++t) {
    int u = tid + 512 * t;
    int img = u >> 7, fcn = u & 127;
    float s = 0.f;
#pragma unroll
    for (int q2 = 0; q2 < 4; ++q2)
      s += (float)part[((q2 * 64 + ig) * 16 + img) * 128 + fcn];
    h_s[img * 136 + fcn] = f2bf(fmaxf(s + b1[fcn], 0.f));
  }
  __syncthreads();
  if (wave < 6) {
    const short8* wf2 = (const short8*)(ws16 + WFC2_E);
    const short8* h8 = (const short8*)h_s;
    f32x4 a2 = {0.f, 0.f, 0.f, 0.f};
#pragma unroll
    for (int ks = 0; ks < 4; ++ks) {
      short8 b = wf2[(wave * 4 + ks) * 64 + lane];
      short8 a = h8[l15 * 17 + ks * 4 + g];
      a2 = __builtin_amdgcn_mfma_f32_16x16x32_bf16(a, b, a2, 0, 0, 0);
    }
    int cls = wave * 16 + l15;
    if (cls < 83) {
      float bias2 = b2[cls];
#pragma unroll
      for (int i = 0; i < 4; ++i) {
        int nimg = ig * 16 + 4 * g + i;
        out[((nimg >> 5) * 83 + cls) * 32 + (nimg & 31)] = a2[i] + bias2;
      }
    }
  }
}

extern "C" void kernel_launch(void* const* d_in, const int* in_sizes, int n_in,
                              void* d_out, int out_size, void* d_ws, size_t ws_size,
                              hipStream_t stream)
{
  const float* x    = (const float*)d_in[0];
  const float* w1   = (const float*)d_in[1];
  const float* c1b  = (const float*)d_in[2];
  const float* w2   = (const float*)d_in[3];
  const float* c2b  = (const float*)d_in[4];
  const float* wfc1 = (const float*)d_in[5];
  const float* bfc1 = (const float*)d_in[6];
  const float* wfc2 = (const float*)d_in[7];
  const float* bfc2 = (const float*)d_in[8];
  unsigned short* ws16 = (unsigned short*)d_ws;
  float* out = (float*)d_out;

  prep_kernel<<<6472, 256, 0, stream>>>(w1, c1b, w2, wfc1, wfc2, ws16);
  conv_kernel<<<2048, 512, 79616, stream>>>(x, c2b, ws16);
  fc1_kernel<<<256, 512, 100608, stream>>>(ws16);
  fc2_kernel<<<64, 512, 0, stream>>>(bfc1, bfc2, ws16, out);
}